// Round 1
// baseline (1911.125 us; speedup 1.0000x reference)
//
#include <hip/hip_runtime.h>

typedef __attribute__((ext_vector_type(8))) short short8;
typedef __attribute__((ext_vector_type(4))) float f32x4;

#define DEVI static __device__ __forceinline__

DEVI float b2f(short s) { return __uint_as_float(((unsigned)(unsigned short)s) << 16); }
DEVI short f2bs(float x) {
  unsigned u = __float_as_uint(x);
  unsigned r = (u + 0x7FFFu + ((u >> 16) & 1u)) >> 16;
  return (short)(unsigned short)r;
}

// ---------------- per-row mean/rstd for 1024-wide fp32 rows ----------------
__global__ __launch_bounds__(256) void stats_kernel(const float* __restrict__ X,
                                                    float2* __restrict__ out) {
  const size_t row = (size_t)blockIdx.x * 4 + (threadIdx.x >> 6);
  const int lane = threadIdx.x & 63;
  const float* r = X + row * 1024;
  float s = 0.f, ss = 0.f;
#pragma unroll
  for (int j = 0; j < 4; j++) {
    f32x4 x = *(const f32x4*)(r + j * 256 + lane * 4);
#pragma unroll
    for (int c = 0; c < 4; c++) { s += x[c]; ss += x[c] * x[c]; }
  }
  for (int o = 32; o > 0; o >>= 1) { s += __shfl_xor(s, o, 64); ss += __shfl_xor(ss, o, 64); }
  if (lane == 0) {
    float m = s * (1.f / 1024.f);
    float var = ss * (1.f / 1024.f) - m * m;
    out[row] = make_float2(m, rsqrtf(var + 1e-5f));
  }
}

// ---------------- W [K][N] fp32  ->  Wt [N][K] bf16 ------------------------
__global__ __launch_bounds__(256) void wtrans_kernel(const float* __restrict__ W,
                                                     short* __restrict__ Wt) {
  __shared__ float tile[32][33];
  const int tx = threadIdx.x & 31;
  const int ty = threadIdx.x >> 5;  // 0..7
  const int c0 = blockIdx.x * 32, r0 = blockIdx.y * 32;
#pragma unroll
  for (int rr = 0; rr < 4; rr++)
    tile[ty + rr * 8][tx] = W[(size_t)(r0 + ty + rr * 8) * 1024 + c0 + tx];
  __syncthreads();
#pragma unroll
  for (int rr = 0; rr < 4; rr++)
    Wt[(size_t)(c0 + ty + rr * 8) * 1024 + r0 + tx] = f2bs(tile[tx][ty + rr * 8]);
}

// ---------------- generic 128x128 MFMA GEMM --------------------------------
// AMODE 0: A bf16 [M][K]            AMODE 1: A fp32 [M][K] with fused LayerNorm
// BMODE 0: Bt bf16 [N][K] (K-contiguous)   BMODE 1: B bf16 [K][ldb_src] (V), LDS-transposed
// EPI 0: + bias[col], bf16 out      EPI 1: *scale, mask -> -1e9, bf16 out   EPI 2: fp32 out
template <int AMODE, int BMODE, int EPI>
__global__ __launch_bounds__(256) void gemm_kernel(
    const void* __restrict__ Ap, const void* __restrict__ Bp, void* __restrict__ Cp,
    int K, int ldc, int ldb_src, long Abatch, long Bbatch, long Cbatch,
    const float2* __restrict__ stats, const float* __restrict__ lng,
    const float* __restrict__ lnb, const float* __restrict__ bias,
    const int* __restrict__ mask, float scale) {
  __shared__ short As[128 * 40];
  __shared__ short Bs[128 * 40];
  const int t = threadIdx.x;
  const int bz = blockIdx.z;
  const int rowBase = blockIdx.y * 128;
  const int colBase = blockIdx.x * 128;

  const int w = t >> 6;
  const int wl = t & 63;
  const int wm = (w >> 1) * 64;
  const int wn = (w & 1) * 64;
  const int fr = wl & 15;
  const int fg = wl >> 4;

  f32x4 acc[4][4];
#pragma unroll
  for (int m = 0; m < 4; m++)
#pragma unroll
    for (int n = 0; n < 4; n++) acc[m][n] = (f32x4){0.f, 0.f, 0.f, 0.f};

  const int ar = t >> 1;
  const int as = (t & 1) * 16;
  const int nkt = K >> 5;

  for (int kt = 0; kt < nkt; ++kt) {
    // ---- stage A tile [128][32]
    if (AMODE == 0) {
      const short* A = (const short*)Ap + (size_t)bz * Abatch;
      const short* src = A + (size_t)(rowBase + ar) * K + kt * 32 + as;
      *(short8*)&As[ar * 40 + as] = *(const short8*)src;
      *(short8*)&As[ar * 40 + as + 8] = *(const short8*)(src + 8);
    } else {
      const float* A = (const float*)Ap;
      const size_t rowG = (size_t)rowBase + ar;
      const float* src = A + rowG * (size_t)K + kt * 32 + as;
      const float2 st = stats[rowG];
      short tmp[16];
#pragma unroll
      for (int j = 0; j < 16; j += 4) {
        f32x4 x = *(const f32x4*)(src + j);
        f32x4 gg = *(const f32x4*)(lng + kt * 32 + as + j);
        f32x4 bb = *(const f32x4*)(lnb + kt * 32 + as + j);
#pragma unroll
        for (int c = 0; c < 4; c++)
          tmp[j + c] = f2bs((x[c] - st.x) * st.y * gg[c] + bb[c]);
      }
      *(short8*)&As[ar * 40 + as] = *(short8*)&tmp[0];
      *(short8*)&As[ar * 40 + as + 8] = *(short8*)&tmp[8];
    }
    // ---- stage B tile -> Bs[n][k] (K-contiguous rows)
    if (BMODE == 0) {
      const short* Bt = (const short*)Bp + (size_t)bz * Bbatch;
      const short* src = Bt + (size_t)(colBase + ar) * K + kt * 32 + as;
      *(short8*)&Bs[ar * 40 + as] = *(const short8*)src;
      *(short8*)&Bs[ar * 40 + as + 8] = *(const short8*)(src + 8);
    } else {
      const int vs = t >> 3;          // 0..31  (k row)
      const int vd = (t & 7) * 16;    // col segment
      const short* V = (const short*)Bp + (size_t)bz * Bbatch;
      const short* src = V + (size_t)(kt * 32 + vs) * ldb_src + colBase + vd;
      short8 lo = *(const short8*)src;
      short8 hi = *(const short8*)(src + 8);
#pragma unroll
      for (int j = 0; j < 8; j++) {
        Bs[(vd + j) * 40 + vs] = lo[j];
        Bs[(vd + 8 + j) * 40 + vs] = hi[j];
      }
    }
    __syncthreads();
    short8 af[4], bfr[4];
#pragma unroll
    for (int m = 0; m < 4; m++)
      af[m] = *(const short8*)&As[(wm + m * 16 + fr) * 40 + fg * 8];
#pragma unroll
    for (int n = 0; n < 4; n++)
      bfr[n] = *(const short8*)&Bs[(wn + n * 16 + fr) * 40 + fg * 8];
#pragma unroll
    for (int m = 0; m < 4; m++)
#pragma unroll
      for (int n = 0; n < 4; n++)
        acc[m][n] = __builtin_amdgcn_mfma_f32_16x16x32_bf16(af[m], bfr[n], acc[m][n], 0, 0, 0);
    __syncthreads();
  }

  // ---- epilogue
  if (EPI == 0) {
    short* C = (short*)Cp;
#pragma unroll
    for (int n = 0; n < 4; n++) {
      const int col = colBase + wn + n * 16 + fr;
      const float bb = bias[col];
#pragma unroll
      for (int m = 0; m < 4; m++)
#pragma unroll
        for (int i = 0; i < 4; i++) {
          const size_t row = (size_t)rowBase + wm + m * 16 + fg * 4 + i;
          C[row * (size_t)ldc + col] = f2bs(acc[m][n][i] + bb);
        }
    }
  } else if (EPI == 1) {
    short* C = (short*)Cp + (size_t)bz * Cbatch;
#pragma unroll
    for (int n = 0; n < 4; n++) {
      const int col = colBase + wn + n * 16 + fr;
      const bool mk = mask[bz * 2048 + col] != 0;
#pragma unroll
      for (int m = 0; m < 4; m++)
#pragma unroll
        for (int i = 0; i < 4; i++) {
          const size_t row = (size_t)rowBase + wm + m * 16 + fg * 4 + i;
          const float sv = mk ? acc[m][n][i] * scale : -1e9f;
          C[row * (size_t)ldc + col] = f2bs(sv);
        }
    }
  } else {
    float* C = (float*)Cp + (size_t)bz * Cbatch;
#pragma unroll
    for (int n = 0; n < 4; n++) {
      const int col = colBase + wn + n * 16 + fr;
#pragma unroll
      for (int m = 0; m < 4; m++)
#pragma unroll
        for (int i = 0; i < 4; i++) {
          const size_t row = (size_t)rowBase + wm + m * 16 + fg * 4 + i;
          C[row * (size_t)ldc + col] = acc[m][n][i];
        }
    }
  }
}

// ---------------- rowwise softmax over 2048 bf16, in place -----------------
__global__ __launch_bounds__(256) void softmax_kernel(short* __restrict__ P) {
  const size_t row = (size_t)blockIdx.x * 4 + (threadIdx.x >> 6);
  const int lane = threadIdx.x & 63;
  short* r = P + row * 2048;
  short8 v[4];
#pragma unroll
  for (int j = 0; j < 4; j++) v[j] = *(const short8*)(r + j * 512 + lane * 8);
  float f[32];
  float mx = -3.0e38f;
#pragma unroll
  for (int j = 0; j < 4; j++)
#pragma unroll
    for (int i = 0; i < 8; i++) {
      float x = b2f(v[j][i]);
      f[j * 8 + i] = x;
      mx = fmaxf(mx, x);
    }
  for (int o = 32; o > 0; o >>= 1) mx = fmaxf(mx, __shfl_xor(mx, o, 64));
  float s = 0.f;
#pragma unroll
  for (int jj = 0; jj < 32; jj++) {
    float e = __expf(f[jj] - mx);
    f[jj] = e;
    s += e;
  }
  for (int o = 32; o > 0; o >>= 1) s += __shfl_xor(s, o, 64);
  const float inv = 1.f / s;
#pragma unroll
  for (int j = 0; j < 4; j++) {
    short8 o8;
#pragma unroll
    for (int i = 0; i < 8; i++) o8[i] = f2bs(f[j * 8 + i] * inv);
    *(short8*)(r + j * 512 + lane * 8) = o8;
  }
}

// ---------------- in-place LayerNorm on fp32 1024-wide rows ----------------
__global__ __launch_bounds__(256) void final_ln_kernel(float* __restrict__ Y,
                                                       const float* __restrict__ g,
                                                       const float* __restrict__ b) {
  const size_t row = (size_t)blockIdx.x * 4 + (threadIdx.x >> 6);
  const int lane = threadIdx.x & 63;
  float* r = Y + row * 1024;
  f32x4 x[4];
  float s = 0.f, ss = 0.f;
#pragma unroll
  for (int j = 0; j < 4; j++) {
    x[j] = *(const f32x4*)(r + j * 256 + lane * 4);
#pragma unroll
    for (int c = 0; c < 4; c++) { s += x[j][c]; ss += x[j][c] * x[j][c]; }
  }
  for (int o = 32; o > 0; o >>= 1) { s += __shfl_xor(s, o, 64); ss += __shfl_xor(ss, o, 64); }
  const float m = s * (1.f / 1024.f);
  const float rstd = rsqrtf(ss * (1.f / 1024.f) - m * m + 1e-5f);
#pragma unroll
  for (int j = 0; j < 4; j++) {
    f32x4 gg = *(const f32x4*)(g + j * 256 + lane * 4);
    f32x4 bb = *(const f32x4*)(b + j * 256 + lane * 4);
    f32x4 y;
#pragma unroll
    for (int c = 0; c < 4; c++) y[c] = (x[j][c] - m) * rstd * gg[c] + bb[c];
    *(f32x4*)(r + j * 256 + lane * 4) = y;
  }
}

extern "C" void kernel_launch(void* const* d_in, const int* in_sizes, int n_in,
                              void* d_out, int out_size, void* d_ws, size_t ws_size,
                              hipStream_t stream) {
  const float* text = (const float*)d_in[0];
  const float* audio = (const float*)d_in[1];
  const int* amask = (const int*)d_in[2];
  const float* ln_t_g = (const float*)d_in[3];
  const float* ln_t_b = (const float*)d_in[4];
  const float* ln_a_g = (const float*)d_in[5];
  const float* ln_a_b = (const float*)d_in[6];
  const float* Wq = (const float*)d_in[7];
  const float* bq = (const float*)d_in[8];
  const float* Wk = (const float*)d_in[9];
  const float* bk = (const float*)d_in[10];
  const float* Wv = (const float*)d_in[11];
  const float* bv = (const float*)d_in[12];
  const float* ln_p_g = (const float*)d_in[13];
  const float* ln_p_b = (const float*)d_in[14];

  char* p = (char*)d_ws;
  float2* statsT = (float2*)p; p += (size_t)32768 * 8;
  float2* statsA = (float2*)p; p += (size_t)65536 * 8;
  short* Wqt = (short*)p; p += (size_t)1024 * 1024 * 2;
  short* Wkt = (short*)p; p += (size_t)1024 * 1024 * 2;
  short* Wvt = (short*)p; p += (size_t)1024 * 1024 * 2;
  short* qb = (short*)p; p += (size_t)32768 * 1024 * 2;
  short* kb = (short*)p; p += (size_t)65536 * 1024 * 2;
  short* vb = (short*)p; p += (size_t)65536 * 1024 * 2;
  short* Pb = (short*)p; p += (size_t)32768 * 2048 * 2;
  (void)ws_size; (void)in_sizes; (void)n_in; (void)out_size;

  // 1. LN stats
  stats_kernel<<<8192, 256, 0, stream>>>(text, statsT);
  stats_kernel<<<16384, 256, 0, stream>>>(audio, statsA);
  // 2. weight transpose+convert
  wtrans_kernel<<<dim3(32, 32), 256, 0, stream>>>(Wq, Wqt);
  wtrans_kernel<<<dim3(32, 32), 256, 0, stream>>>(Wk, Wkt);
  wtrans_kernel<<<dim3(32, 32), 256, 0, stream>>>(Wv, Wvt);
  // 3. q = LN(text) @ Wq + bq   [32768 x 1024]
  gemm_kernel<1, 0, 0><<<dim3(8, 256, 1), 256, 0, stream>>>(
      text, Wqt, qb, 1024, 1024, 0, 0, 0, 0, statsT, ln_t_g, ln_t_b, bq, nullptr, 0.f);
  // 4. k = LN(audio) @ Wk + bk  [65536 x 1024]
  gemm_kernel<1, 0, 0><<<dim3(8, 512, 1), 256, 0, stream>>>(
      audio, Wkt, kb, 1024, 1024, 0, 0, 0, 0, statsA, ln_a_g, ln_a_b, bk, nullptr, 0.f);
  // 5. v = LN(audio) @ Wv + bv  [65536 x 1024]
  gemm_kernel<1, 0, 0><<<dim3(8, 512, 1), 256, 0, stream>>>(
      audio, Wvt, vb, 1024, 1024, 0, 0, 0, 0, statsA, ln_a_g, ln_a_b, bv, nullptr, 0.f);
  // 6. scores = q @ k^T * scale, masked -> P (bf16) [32][1024][2048]
  gemm_kernel<0, 0, 1><<<dim3(16, 8, 32), 256, 0, stream>>>(
      qb, kb, Pb, 1024, 2048, 0, (long)1024 * 1024, (long)2048 * 1024, (long)1024 * 2048,
      nullptr, nullptr, nullptr, nullptr, amask, 0.03125f);
  // 7. softmax rows of P, in place
  softmax_kernel<<<8192, 256, 0, stream>>>(Pb);
  // 8. cross = P @ v -> d_out (fp32) [32][1024][1024]
  gemm_kernel<0, 1, 2><<<dim3(8, 8, 32), 256, 0, stream>>>(
      Pb, vb, d_out, 2048, 1024, 1024, (long)1024 * 2048, (long)2048 * 1024,
      (long)1024 * 1024, nullptr, nullptr, nullptr, nullptr, nullptr, 0.f);
  // 9. final LayerNorm in place on d_out
  final_ln_kernel<<<8192, 256, 0, stream>>>((float*)d_out, ln_p_g, ln_p_b);
}

// Round 2
// 1214.368 us; speedup vs baseline: 1.5738x; 1.5738x over previous
//
#include <hip/hip_runtime.h>

typedef __attribute__((ext_vector_type(8))) short short8;
typedef __attribute__((ext_vector_type(4))) short short4_t;
typedef __attribute__((ext_vector_type(4))) float f32x4;

#define DEVI static __device__ __forceinline__

DEVI float b2f(short s) { return __uint_as_float(((unsigned)(unsigned short)s) << 16); }
DEVI short f2bs(float x) {
  unsigned u = __float_as_uint(x);
  unsigned r = (u + 0x7FFFu + ((u >> 16) & 1u)) >> 16;
  return (short)(unsigned short)r;
}

DEVI void gload16(const short* g, short* l) {
  __builtin_amdgcn_global_load_lds(
      (const __attribute__((address_space(1))) void*)g,
      (__attribute__((address_space(3))) void*)l, 16, 0, 0);
}

// ---------- fused LayerNorm -> bf16, one wave per 1024-wide row ------------
__global__ __launch_bounds__(256) void ln_bf16_kernel(const float* __restrict__ X,
                                                      const float* __restrict__ g,
                                                      const float* __restrict__ b,
                                                      short* __restrict__ Y) {
  const size_t row = (size_t)blockIdx.x * 4 + (threadIdx.x >> 6);
  const int lane = threadIdx.x & 63;
  const float* r = X + row * 1024;
  f32x4 x[4];
  float s = 0.f, ss = 0.f;
#pragma unroll
  for (int j = 0; j < 4; j++) {
    x[j] = *(const f32x4*)(r + j * 256 + lane * 4);
#pragma unroll
    for (int c = 0; c < 4; c++) { s += x[j][c]; ss += x[j][c] * x[j][c]; }
  }
  for (int o = 32; o > 0; o >>= 1) { s += __shfl_xor(s, o, 64); ss += __shfl_xor(ss, o, 64); }
  const float m = s * (1.f / 1024.f);
  const float rstd = rsqrtf(ss * (1.f / 1024.f) - m * m + 1e-5f);
#pragma unroll
  for (int j = 0; j < 4; j++) {
    f32x4 gg = *(const f32x4*)(g + j * 256 + lane * 4);
    f32x4 bb = *(const f32x4*)(b + j * 256 + lane * 4);
    short4_t o4;
#pragma unroll
    for (int c = 0; c < 4; c++) o4[c] = f2bs((x[j][c] - m) * rstd * gg[c] + bb[c]);
    *(short4_t*)(Y + row * 1024 + j * 256 + lane * 4) = o4;
  }
}

// ---------------- W [K][N] fp32  ->  Wt [N][K] bf16 ------------------------
__global__ __launch_bounds__(256) void wtrans_kernel(const float* __restrict__ W,
                                                     short* __restrict__ Wt) {
  __shared__ float tile[32][33];
  const int tx = threadIdx.x & 31;
  const int ty = threadIdx.x >> 5;  // 0..7
  const int c0 = blockIdx.x * 32, r0 = blockIdx.y * 32;
#pragma unroll
  for (int rr = 0; rr < 4; rr++)
    tile[ty + rr * 8][tx] = W[(size_t)(r0 + ty + rr * 8) * 1024 + c0 + tx];
  __syncthreads();
#pragma unroll
  for (int rr = 0; rr < 4; rr++)
    Wt[(size_t)(c0 + ty + rr * 8) * 1024 + r0 + tx] = f2bs(tile[tx][ty + rr * 8]);
}

// ---------------- canonical m97-style 128x128 MFMA GEMM --------------------
// A bf16 [M][K] K-contig, B bf16 [N][K] K-contig, 128^2 tile, BK=32,
// 4 waves 2x2, global_load_lds width-16 into linear LDS.
// EPI 0: +bias[col] -> bf16   EPI 1: *scale, mask[col]==0 -> -1e9 -> bf16
// EPI 2: fp32 out             EPI 3: +bias[row] -> bf16
template <int EPI>
__global__ __launch_bounds__(256) void gemm_kernel(
    const short* __restrict__ A, const short* __restrict__ B, void* __restrict__ Cp,
    int K, int ldc, long Abatch, long Bbatch, long Cbatch,
    const float* __restrict__ bias, const int* __restrict__ mask, float scale) {
  __shared__ short As[128 * 32];
  __shared__ short Bs[128 * 32];
  const int t = threadIdx.x;
  const int bz = blockIdx.z;
  const int rowBase = blockIdx.y * 128;
  const int colBase = blockIdx.x * 128;
  const int w = t >> 6, l = t & 63;
  const int wm = (w >> 1) * 64, wn = (w & 1) * 64;
  const int fr = l & 15, fg = l >> 4;

  A += (size_t)bz * Abatch;
  B += (size_t)bz * Bbatch;

  f32x4 acc[4][4];
#pragma unroll
  for (int m = 0; m < 4; m++)
#pragma unroll
    for (int n = 0; n < 4; n++) acc[m][n] = (f32x4){0.f, 0.f, 0.f, 0.f};

  // staging: wave w owns rows [w*32, w*32+32); lane l -> row w*32+c*16+(l>>2),
  // k-seg (l&3)*8.  LDS element = w*1024 + c*512 + l*8 (linear, lane x 16B).
  const int srow = w * 32 + (l >> 2);
  const int scol = (l & 3) * 8;
  const short* aptr = A + (size_t)(rowBase + srow) * K + scol;
  const short* bptr = B + (size_t)(colBase + srow) * K + scol;
  short* asb = &As[w * 1024];
  short* bsb = &Bs[w * 1024];

  const int nkt = K >> 5;
  for (int kt = 0; kt < nkt; ++kt) {
    gload16(aptr, asb);
    gload16(aptr + 16 * (size_t)K, asb + 512);
    gload16(bptr, bsb);
    gload16(bptr + 16 * (size_t)K, bsb + 512);
    aptr += 32;
    bptr += 32;
    __syncthreads();
    short8 af[4], bf[4];
#pragma unroll
    for (int m = 0; m < 4; m++)
      af[m] = *(const short8*)&As[(wm + m * 16 + fr) * 32 + fg * 8];
#pragma unroll
    for (int n = 0; n < 4; n++)
      bf[n] = *(const short8*)&Bs[(wn + n * 16 + fr) * 32 + fg * 8];
#pragma unroll
    for (int m = 0; m < 4; m++)
#pragma unroll
      for (int n = 0; n < 4; n++)
        acc[m][n] = __builtin_amdgcn_mfma_f32_16x16x32_bf16(af[m], bf[n], acc[m][n], 0, 0, 0);
    __syncthreads();
  }

  // ---- epilogue: C/D layout col=lane&15, row=(lane>>4)*4+i
  if (EPI == 0) {
    short* C = (short*)Cp + (size_t)bz * Cbatch;
#pragma unroll
    for (int n = 0; n < 4; n++) {
      const int col = colBase + wn + n * 16 + fr;
      const float bb = bias[col];
#pragma unroll
      for (int m = 0; m < 4; m++)
#pragma unroll
        for (int i = 0; i < 4; i++) {
          const size_t row = (size_t)rowBase + wm + m * 16 + fg * 4 + i;
          C[row * (size_t)ldc + col] = f2bs(acc[m][n][i] + bb);
        }
    }
  } else if (EPI == 1) {
    short* C = (short*)Cp + (size_t)bz * Cbatch;
#pragma unroll
    for (int n = 0; n < 4; n++) {
      const int col = colBase + wn + n * 16 + fr;
      const bool mk = mask[(size_t)bz * 2048 + col] != 0;
#pragma unroll
      for (int m = 0; m < 4; m++)
#pragma unroll
        for (int i = 0; i < 4; i++) {
          const size_t row = (size_t)rowBase + wm + m * 16 + fg * 4 + i;
          const float sv = mk ? acc[m][n][i] * scale : -1e9f;
          C[row * (size_t)ldc + col] = f2bs(sv);
        }
    }
  } else if (EPI == 2) {
    float* C = (float*)Cp + (size_t)bz * Cbatch;
#pragma unroll
    for (int n = 0; n < 4; n++) {
      const int col = colBase + wn + n * 16 + fr;
#pragma unroll
      for (int m = 0; m < 4; m++)
#pragma unroll
        for (int i = 0; i < 4; i++) {
          const size_t row = (size_t)rowBase + wm + m * 16 + fg * 4 + i;
          C[row * (size_t)ldc + col] = acc[m][n][i];
        }
    }
  } else {
    short* C = (short*)Cp + (size_t)bz * Cbatch;
#pragma unroll
    for (int m = 0; m < 4; m++) {
      f32x4 b4 = *(const f32x4*)&bias[rowBase + wm + m * 16 + fg * 4];
#pragma unroll
      for (int n = 0; n < 4; n++) {
        const int col = colBase + wn + n * 16 + fr;
#pragma unroll
        for (int i = 0; i < 4; i++) {
          const size_t row = (size_t)rowBase + wm + m * 16 + fg * 4 + i;
          C[row * (size_t)ldc + col] = f2bs(acc[m][n][i] + b4[i]);
        }
      }
    }
  }
}

// ---------------- rowwise softmax over 2048 bf16, in place -----------------
__global__ __launch_bounds__(256) void softmax_kernel(short* __restrict__ P) {
  const size_t row = (size_t)blockIdx.x * 4 + (threadIdx.x >> 6);
  const int lane = threadIdx.x & 63;
  short* r = P + row * 2048;
  short8 v[4];
#pragma unroll
  for (int j = 0; j < 4; j++) v[j] = *(const short8*)(r + j * 512 + lane * 8);
  float f[32];
  float mx = -3.0e38f;
#pragma unroll
  for (int j = 0; j < 4; j++)
#pragma unroll
    for (int i = 0; i < 8; i++) {
      float x = b2f(v[j][i]);
      f[j * 8 + i] = x;
      mx = fmaxf(mx, x);
    }
  for (int o = 32; o > 0; o >>= 1) mx = fmaxf(mx, __shfl_xor(mx, o, 64));
  float s = 0.f;
#pragma unroll
  for (int jj = 0; jj < 32; jj++) {
    float e = __expf(f[jj] - mx);
    f[jj] = e;
    s += e;
  }
  for (int o = 32; o > 0; o >>= 1) s += __shfl_xor(s, o, 64);
  const float inv = 1.f / s;
#pragma unroll
  for (int j = 0; j < 4; j++) {
    short8 o8;
#pragma unroll
    for (int i = 0; i < 8; i++) o8[i] = f2bs(f[j * 8 + i] * inv);
    *(short8*)(r + j * 512 + lane * 8) = o8;
  }
}

// ---------------- in-place LayerNorm on fp32 1024-wide rows ----------------
__global__ __launch_bounds__(256) void final_ln_kernel(float* __restrict__ Y,
                                                       const float* __restrict__ g,
                                                       const float* __restrict__ b) {
  const size_t row = (size_t)blockIdx.x * 4 + (threadIdx.x >> 6);
  const int lane = threadIdx.x & 63;
  float* r = Y + row * 1024;
  f32x4 x[4];
  float s = 0.f, ss = 0.f;
#pragma unroll
  for (int j = 0; j < 4; j++) {
    x[j] = *(const f32x4*)(r + j * 256 + lane * 4);
#pragma unroll
    for (int c = 0; c < 4; c++) { s += x[j][c]; ss += x[j][c] * x[j][c]; }
  }
  for (int o = 32; o > 0; o >>= 1) { s += __shfl_xor(s, o, 64); ss += __shfl_xor(ss, o, 64); }
  const float m = s * (1.f / 1024.f);
  const float rstd = rsqrtf(ss * (1.f / 1024.f) - m * m + 1e-5f);
#pragma unroll
  for (int j = 0; j < 4; j++) {
    f32x4 gg = *(const f32x4*)(g + j * 256 + lane * 4);
    f32x4 bb = *(const f32x4*)(b + j * 256 + lane * 4);
    f32x4 y;
#pragma unroll
    for (int c = 0; c < 4; c++) y[c] = (x[j][c] - m) * rstd * gg[c] + bb[c];
    *(f32x4*)(r + j * 256 + lane * 4) = y;
  }
}

extern "C" void kernel_launch(void* const* d_in, const int* in_sizes, int n_in,
                              void* d_out, int out_size, void* d_ws, size_t ws_size,
                              hipStream_t stream) {
  const float* text = (const float*)d_in[0];
  const float* audio = (const float*)d_in[1];
  const int* amask = (const int*)d_in[2];
  const float* ln_t_g = (const float*)d_in[3];
  const float* ln_t_b = (const float*)d_in[4];
  const float* ln_a_g = (const float*)d_in[5];
  const float* ln_a_b = (const float*)d_in[6];
  const float* Wq = (const float*)d_in[7];
  const float* bq = (const float*)d_in[8];
  const float* Wk = (const float*)d_in[9];
  const float* bk = (const float*)d_in[10];
  const float* Wv = (const float*)d_in[11];
  const float* bv = (const float*)d_in[12];
  const float* ln_p_g = (const float*)d_in[13];
  const float* ln_p_b = (const float*)d_in[14];

  char* p = (char*)d_ws;
  short* tb = (short*)p;  p += (size_t)32768 * 1024 * 2;   // 64 MB  (LN text, bf16)
  short* ab = (short*)p;  p += (size_t)65536 * 1024 * 2;   // 128 MB (LN audio, bf16)
  short* Wqt = (short*)p; p += (size_t)1024 * 1024 * 2;
  short* Wkt = (short*)p; p += (size_t)1024 * 1024 * 2;
  short* Wvt = (short*)p; p += (size_t)1024 * 1024 * 2;
  short* qb = (short*)p;  p += (size_t)32768 * 1024 * 2;   // 64 MB
  short* kb = (short*)p;  p += (size_t)65536 * 1024 * 2;   // 128 MB
  short* vTb = (short*)p; p += (size_t)32 * 1024 * 2048 * 2;  // 128 MB, [b][d][s]
  // P aliases tb+ab (dead once qb/kb/vTb are built; scores runs after)
  short* Pb = tb;
  (void)ws_size; (void)in_sizes; (void)n_in; (void)out_size;

  // 1. LN -> bf16
  ln_bf16_kernel<<<8192, 256, 0, stream>>>(text, ln_t_g, ln_t_b, tb);
  ln_bf16_kernel<<<16384, 256, 0, stream>>>(audio, ln_a_g, ln_a_b, ab);
  // 2. weight transpose+convert
  wtrans_kernel<<<dim3(32, 32), 256, 0, stream>>>(Wq, Wqt);
  wtrans_kernel<<<dim3(32, 32), 256, 0, stream>>>(Wk, Wkt);
  wtrans_kernel<<<dim3(32, 32), 256, 0, stream>>>(Wv, Wvt);
  // 3. q = tb @ Wqt^T + bq   [32768 x 1024]
  gemm_kernel<0><<<dim3(8, 256, 1), 256, 0, stream>>>(
      tb, Wqt, qb, 1024, 1024, 0, 0, 0, bq, nullptr, 0.f);
  // 4. k = ab @ Wkt^T + bk   [65536 x 1024]
  gemm_kernel<0><<<dim3(8, 512, 1), 256, 0, stream>>>(
      ab, Wkt, kb, 1024, 1024, 0, 0, 0, bk, nullptr, 0.f);
  // 5. vT[b][d][s] = (ab @ Wvt^T + bv)^T : A=Wvt (M=1024 d), B=ab[b] (N=2048 s)
  gemm_kernel<3><<<dim3(16, 8, 32), 256, 0, stream>>>(
      Wvt, ab, vTb, 1024, 2048, 0, (long)2048 * 1024, (long)1024 * 2048,
      bv, nullptr, 0.f);
  // 6. scores = q @ k^T * scale, masked -> P bf16 [32][1024][2048]
  gemm_kernel<1><<<dim3(16, 8, 32), 256, 0, stream>>>(
      qb, kb, Pb, 1024, 2048, (long)1024 * 1024, (long)2048 * 1024,
      (long)1024 * 2048, nullptr, amask, 0.03125f);
  // 7. softmax rows of P, in place
  softmax_kernel<<<8192, 256, 0, stream>>>(Pb);
  // 8. cross = P @ vT^T -> d_out fp32 [32][1024][1024]
  gemm_kernel<2><<<dim3(8, 8, 32), 256, 0, stream>>>(
      Pb, vTb, d_out, 2048, 1024, (long)1024 * 2048, (long)1024 * 2048,
      (long)1024 * 1024, nullptr, nullptr, 0.f);
  // 9. final LayerNorm in place on d_out
  final_ln_kernel<<<8192, 256, 0, stream>>>((float*)d_out, ln_p_g, ln_p_b);
}

// Round 3
// 911.814 us; speedup vs baseline: 2.0960x; 1.3318x over previous
//
#include <hip/hip_runtime.h>

typedef __attribute__((ext_vector_type(8))) short short8;
typedef __attribute__((ext_vector_type(4))) short short4_t;
typedef __attribute__((ext_vector_type(4))) float f32x4;

#define DEVI static __device__ __forceinline__

DEVI float b2f(short s) { return __uint_as_float(((unsigned)(unsigned short)s) << 16); }
DEVI short f2bs(float x) {
  unsigned u = __float_as_uint(x);
  unsigned r = (u + 0x7FFFu + ((u >> 16) & 1u)) >> 16;
  return (short)(unsigned short)r;
}

DEVI void gload16(const short* g, short* l) {
  __builtin_amdgcn_global_load_lds(
      (const __attribute__((address_space(1))) void*)g,
      (__attribute__((address_space(3))) void*)l, 16, 0, 0);
}

DEVI void wg_barrier() {
  asm volatile("" ::: "memory");
  __builtin_amdgcn_s_barrier();
  asm volatile("" ::: "memory");
}

// Stage one 128x64 bf16 unit: 8 waves x 2 gloads x 64 lanes x 16B = 16KB.
// LDS dest linear (wave-uniform + lane*16); global source pre-swizzled:
// lane row = rowbase_w + i*8 + (l>>3); source slot = (l&7) ^ (l>>3).
DEVI void stage_unit(const short* __restrict__ gTile, int K, int rowbase_w,
                     short* lUnit, int w, int l) {
  const int rr = l >> 3;
  const int slot = ((l & 7) ^ rr) << 3;
  const short* g0 = gTile + (size_t)(rowbase_w + rr) * K + slot;
  gload16(g0, lUnit + w * 1024);
  gload16(g0 + (size_t)8 * K, lUnit + w * 1024 + 512);
}

// ---------- fused LayerNorm -> bf16, one wave per 1024-wide row ------------
__global__ __launch_bounds__(256) void ln_bf16_kernel(const float* __restrict__ X,
                                                      const float* __restrict__ g,
                                                      const float* __restrict__ b,
                                                      short* __restrict__ Y) {
  const size_t row = (size_t)blockIdx.x * 4 + (threadIdx.x >> 6);
  const int lane = threadIdx.x & 63;
  const float* r = X + row * 1024;
  f32x4 x[4];
  float s = 0.f, ss = 0.f;
#pragma unroll
  for (int j = 0; j < 4; j++) {
    x[j] = *(const f32x4*)(r + j * 256 + lane * 4);
#pragma unroll
    for (int c = 0; c < 4; c++) { s += x[j][c]; ss += x[j][c] * x[j][c]; }
  }
  for (int o = 32; o > 0; o >>= 1) { s += __shfl_xor(s, o, 64); ss += __shfl_xor(ss, o, 64); }
  const float m = s * (1.f / 1024.f);
  const float rstd = rsqrtf(ss * (1.f / 1024.f) - m * m + 1e-5f);
#pragma unroll
  for (int j = 0; j < 4; j++) {
    f32x4 gg = *(const f32x4*)(g + j * 256 + lane * 4);
    f32x4 bb = *(const f32x4*)(b + j * 256 + lane * 4);
    short4_t o4;
#pragma unroll
    for (int c = 0; c < 4; c++) o4[c] = f2bs((x[j][c] - m) * rstd * gg[c] + bb[c]);
    *(short4_t*)(Y + row * 1024 + j * 256 + lane * 4) = o4;
  }
}

// ---------------- W [K][N] fp32  ->  Wt [N][K] bf16 ------------------------
__global__ __launch_bounds__(256) void wtrans_kernel(const float* __restrict__ W,
                                                     short* __restrict__ Wt) {
  __shared__ float tile[32][33];
  const int tx = threadIdx.x & 31;
  const int ty = threadIdx.x >> 5;  // 0..7
  const int c0 = blockIdx.x * 32, r0 = blockIdx.y * 32;
#pragma unroll
  for (int rr = 0; rr < 4; rr++)
    tile[ty + rr * 8][tx] = W[(size_t)(r0 + ty + rr * 8) * 1024 + c0 + tx];
  __syncthreads();
#pragma unroll
  for (int rr = 0; rr < 4; rr++)
    Wt[(size_t)(c0 + ty + rr * 8) * 1024 + r0 + tx] = f2bs(tile[tx][ty + rr * 8]);
}

// ============ 256x256 8-phase MFMA GEMM (T1+T2+T3+T4+T5) ===================
// A bf16 [M][K] K-contig, B bf16 [N][K] K-contig, BK=64, 8 waves (2Mx4N),
// per-wave out 128x64. LDS 128KB: A[2buf][2reg][128][64] + B same.
// Region-interleaved layout: A reg h holds global rows {h*64..h*64+63} u
// {128+h*64..}; B reg nh holds rows {wn*64+nh*32..+31 : wn}. Each region is
// ds_read in exactly one phase -> provable stage windows.
// EPI 0: +bias[col] bf16 | 1: *scale, mask->-1e9 bf16 | 2: fp32 | 3: +bias[row] bf16
template <int EPI>
__global__ __launch_bounds__(512, 2) void gemm8_kernel(
    const short* __restrict__ A, const short* __restrict__ B, void* __restrict__ Cp,
    int K, int ldc, long Abatch, long Bbatch, long Cbatch,
    const float* __restrict__ bias, const int* __restrict__ mask, float scale) {
  __shared__ short lds[65536];
  const int t = threadIdx.x;
  const int w = t >> 6, l = t & 63;
  const int wm = w >> 2, wn = w & 3;
  const int fr = l & 15, fg = l >> 4, fr7 = l & 7;

  // XCD-chunked block swizzle (nwg % 8 == 0 by construction)
  const int gx = gridDim.x, gy = gridDim.y;
  const int nwg = gx * gy * (int)gridDim.z;
  int lin = blockIdx.x + gx * (blockIdx.y + gy * blockIdx.z);
  lin = (lin & 7) * (nwg >> 3) + (lin >> 3);
  const int bx = lin % gx;
  const int by = (lin / gx) % gy;
  const int bz = lin / (gx * gy);

  const int rowBase = by * 256;
  const int colBase = bx * 256;
  const short* Ab = A + (size_t)bz * Abatch + (size_t)rowBase * K;
  const short* Bb = B + (size_t)bz * Bbatch + (size_t)colBase * K;

  short* As = lds;            // [buf][reg][128][64]
  short* Bs = lds + 32768;

  f32x4 acc[8][4];
#pragma unroll
  for (int m = 0; m < 8; m++)
#pragma unroll
    for (int n = 0; n < 4; n++) acc[m][n] = (f32x4){0.f, 0.f, 0.f, 0.f};

  const int nt = K >> 6;
  const int ntm1 = nt - 1;

  // stage row bases (per wave)
  const int rbA0 = (w >> 2) * 128 + (w & 3) * 16;  // A region 0
  const int rbA1 = rbA0 + 64;                      // A region 1
  const int rbB0 = (w >> 1) * 64 + (w & 1) * 16;   // B region 0
  const int rbB1 = rbB0 + 32;                      // B region 1

  // ---- prologue: 7 units (tile0 all 4, tile1 first 3)
  stage_unit(Ab, K, rbA0, As, w, l);
  stage_unit(Bb, K, rbB0, Bs, w, l);
  stage_unit(Ab, K, rbA1, As + 8192, w, l);
  stage_unit(Bb, K, rbB1, Bs + 8192, w, l);
  {
    const int kp = (nt > 1) ? 64 : 0;
    stage_unit(Ab + kp, K, rbA0, As + 16384, w, l);
    stage_unit(Bb + kp, K, rbB0, Bs + 16384, w, l);
    stage_unit(Ab + kp, K, rbA1, As + 24576, w, l);
  }
  asm volatile("s_waitcnt vmcnt(10)" ::: "memory");
  wg_barrier();

  // fragment read offsets (elements)
  const int rowA = (wm * 64 + fr) * 64;  // + m*1024 + reg*8192
  const int rowB = (wn * 32 + fr) * 64;  // + n*1024 + reg*8192
  const int ks0 = (fg ^ fr7) << 3;
  const int ks1 = ((4 + fg) ^ fr7) << 3;

  short8 aL[4][2], aH[4][2], bF[2][2];

  for (int tt = 0; tt < nt; ++tt) {
    const int c = tt & 1;
    const short* Ac = As + c * 16384;
    const short* Bc = Bs + c * 16384;
    short* Acur = As + c * 16384;
    short* Bcur = Bs + c * 16384;
    short* Bnx = Bs + (c ^ 1) * 16384;
    const int k1 = ((tt + 1 <= ntm1) ? tt + 1 : ntm1) * 64;
    const int k2 = ((tt + 2 <= ntm1) ? tt + 2 : ntm1) * 64;

    // ---- P0: quadrant (mh0,nh0); 12 ds_reads; stage B-r1(t+1)
#pragma unroll
    for (int m = 0; m < 4; m++) {
      aL[m][0] = *(const short8*)&Ac[rowA + m * 1024 + ks0];
      aL[m][1] = *(const short8*)&Ac[rowA + m * 1024 + ks1];
    }
#pragma unroll
    for (int n = 0; n < 2; n++) {
      bF[n][0] = *(const short8*)&Bc[rowB + n * 1024 + ks0];
      bF[n][1] = *(const short8*)&Bc[rowB + n * 1024 + ks1];
    }
    stage_unit(Bb + k1, K, rbB1, Bnx + 8192, w, l);
    wg_barrier();
    __builtin_amdgcn_s_setprio(1);
#pragma unroll
    for (int m = 0; m < 4; m++)
#pragma unroll
      for (int n = 0; n < 2; n++) {
        acc[m][n] = __builtin_amdgcn_mfma_f32_16x16x32_bf16(aL[m][0], bF[n][0], acc[m][n], 0, 0, 0);
        acc[m][n] = __builtin_amdgcn_mfma_f32_16x16x32_bf16(aL[m][1], bF[n][1], acc[m][n], 0, 0, 0);
      }
    __builtin_amdgcn_s_setprio(0);
    asm volatile("s_waitcnt vmcnt(10)" ::: "memory");
    wg_barrier();

    // ---- P1: quadrant (mh1,nh0); 8 ds_reads; stage A-r0(t+2)
#pragma unroll
    for (int m = 0; m < 4; m++) {
      aH[m][0] = *(const short8*)&Ac[8192 + rowA + m * 1024 + ks0];
      aH[m][1] = *(const short8*)&Ac[8192 + rowA + m * 1024 + ks1];
    }
    stage_unit(Ab + k2, K, rbA0, Acur, w, l);
    wg_barrier();
    __builtin_amdgcn_s_setprio(1);
#pragma unroll
    for (int m = 0; m < 4; m++)
#pragma unroll
      for (int n = 0; n < 2; n++) {
        acc[4 + m][n] = __builtin_amdgcn_mfma_f32_16x16x32_bf16(aH[m][0], bF[n][0], acc[4 + m][n], 0, 0, 0);
        acc[4 + m][n] = __builtin_amdgcn_mfma_f32_16x16x32_bf16(aH[m][1], bF[n][1], acc[4 + m][n], 0, 0, 0);
      }
    __builtin_amdgcn_s_setprio(0);
    asm volatile("s_waitcnt vmcnt(10)" ::: "memory");
    wg_barrier();

    // ---- P2: quadrant (mh0,nh1); 4 ds_reads; stage B-r0(t+2)
#pragma unroll
    for (int n = 0; n < 2; n++) {
      bF[n][0] = *(const short8*)&Bc[8192 + rowB + n * 1024 + ks0];
      bF[n][1] = *(const short8*)&Bc[8192 + rowB + n * 1024 + ks1];
    }
    stage_unit(Bb + k2, K, rbB0, Bcur, w, l);
    wg_barrier();
    __builtin_amdgcn_s_setprio(1);
#pragma unroll
    for (int m = 0; m < 4; m++)
#pragma unroll
      for (int n = 0; n < 2; n++) {
        acc[m][2 + n] = __builtin_amdgcn_mfma_f32_16x16x32_bf16(aL[m][0], bF[n][0], acc[m][2 + n], 0, 0, 0);
        acc[m][2 + n] = __builtin_amdgcn_mfma_f32_16x16x32_bf16(aL[m][1], bF[n][1], acc[m][2 + n], 0, 0, 0);
      }
    __builtin_amdgcn_s_setprio(0);
    wg_barrier();

    // ---- P3: quadrant (mh1,nh1); 0 ds_reads; stage A-r1(t+2)
    stage_unit(Ab + k2, K, rbA1, Acur + 8192, w, l);
    wg_barrier();
    __builtin_amdgcn_s_setprio(1);
#pragma unroll
    for (int m = 0; m < 4; m++)
#pragma unroll
      for (int n = 0; n < 2; n++) {
        acc[4 + m][2 + n] = __builtin_amdgcn_mfma_f32_16x16x32_bf16(aH[m][0], bF[n][0], acc[4 + m][2 + n], 0, 0, 0);
        acc[4 + m][2 + n] = __builtin_amdgcn_mfma_f32_16x16x32_bf16(aH[m][1], bF[n][1], acc[4 + m][2 + n], 0, 0, 0);
      }
    __builtin_amdgcn_s_setprio(0);
    asm volatile("s_waitcnt vmcnt(10)" ::: "memory");
    wg_barrier();
  }

  // ---- epilogue: rows rowBase + wm*128 + mi*16 + fg*4 + j, cols colBase + wn*64 + ni*16 + fr
  if (EPI == 0) {
    short* C = (short*)Cp + (size_t)bz * Cbatch;
#pragma unroll
    for (int ni = 0; ni < 4; ni++) {
      const int col = colBase + wn * 64 + ni * 16 + fr;
      const float bb = bias[col];
#pragma unroll
      for (int mi = 0; mi < 8; mi++)
#pragma unroll
        for (int j = 0; j < 4; j++) {
          const size_t row = (size_t)rowBase + wm * 128 + mi * 16 + fg * 4 + j;
          C[row * (size_t)ldc + col] = f2bs(acc[mi][ni][j] + bb);
        }
    }
  } else if (EPI == 1) {
    short* C = (short*)Cp + (size_t)bz * Cbatch;
#pragma unroll
    for (int ni = 0; ni < 4; ni++) {
      const int col = colBase + wn * 64 + ni * 16 + fr;
      const bool mk = mask[(size_t)bz * 2048 + col] != 0;
#pragma unroll
      for (int mi = 0; mi < 8; mi++)
#pragma unroll
        for (int j = 0; j < 4; j++) {
          const size_t row = (size_t)rowBase + wm * 128 + mi * 16 + fg * 4 + j;
          const float sv = mk ? acc[mi][ni][j] * scale : -1e9f;
          C[row * (size_t)ldc + col] = f2bs(sv);
        }
    }
  } else if (EPI == 2) {
    float* C = (float*)Cp + (size_t)bz * Cbatch;
#pragma unroll
    for (int ni = 0; ni < 4; ni++) {
      const int col = colBase + wn * 64 + ni * 16 + fr;
#pragma unroll
      for (int mi = 0; mi < 8; mi++)
#pragma unroll
        for (int j = 0; j < 4; j++) {
          const size_t row = (size_t)rowBase + wm * 128 + mi * 16 + fg * 4 + j;
          C[row * (size_t)ldc + col] = acc[mi][ni][j];
        }
    }
  } else {
    short* C = (short*)Cp + (size_t)bz * Cbatch;
#pragma unroll
    for (int mi = 0; mi < 8; mi++) {
      f32x4 b4 = *(const f32x4*)&bias[rowBase + wm * 128 + mi * 16 + fg * 4];
#pragma unroll
      for (int ni = 0; ni < 4; ni++) {
        const int col = colBase + wn * 64 + ni * 16 + fr;
#pragma unroll
        for (int j = 0; j < 4; j++) {
          const size_t row = (size_t)rowBase + wm * 128 + mi * 16 + fg * 4 + j;
          C[row * (size_t)ldc + col] = f2bs(acc[mi][ni][j] + b4[j]);
        }
      }
    }
  }
}

// ---------------- rowwise softmax over 2048 bf16, in place -----------------
__global__ __launch_bounds__(256) void softmax_kernel(short* __restrict__ P) {
  const size_t row = (size_t)blockIdx.x * 4 + (threadIdx.x >> 6);
  const int lane = threadIdx.x & 63;
  short* r = P + row * 2048;
  short8 v[4];
#pragma unroll
  for (int j = 0; j < 4; j++) v[j] = *(const short8*)(r + j * 512 + lane * 8);
  float f[32];
  float mx = -3.0e38f;
#pragma unroll
  for (int j = 0; j < 4; j++)
#pragma unroll
    for (int i = 0; i < 8; i++) {
      float x = b2f(v[j][i]);
      f[j * 8 + i] = x;
      mx = fmaxf(mx, x);
    }
  for (int o = 32; o > 0; o >>= 1) mx = fmaxf(mx, __shfl_xor(mx, o, 64));
  float s = 0.f;
#pragma unroll
  for (int jj = 0; jj < 32; jj++) {
    float e = __expf(f[jj] - mx);
    f[jj] = e;
    s += e;
  }
  for (int o = 32; o > 0; o >>= 1) s += __shfl_xor(s, o, 64);
  const float inv = 1.f / s;
#pragma unroll
  for (int j = 0; j < 4; j++) {
    short8 o8;
#pragma unroll
    for (int i = 0; i < 8; i++) o8[i] = f2bs(f[j * 8 + i] * inv);
    *(short8*)(r + j * 512 + lane * 8) = o8;
  }
}

// ---------------- in-place LayerNorm on fp32 1024-wide rows ----------------
__global__ __launch_bounds__(256) void final_ln_kernel(float* __restrict__ Y,
                                                       const float* __restrict__ g,
                                                       const float* __restrict__ b) {
  const size_t row = (size_t)blockIdx.x * 4 + (threadIdx.x >> 6);
  const int lane = threadIdx.x & 63;
  float* r = Y + row * 1024;
  f32x4 x[4];
  float s = 0.f, ss = 0.f;
#pragma unroll
  for (int j = 0; j < 4; j++) {
    x[j] = *(const f32x4*)(r + j * 256 + lane * 4);
#pragma unroll
    for (int c = 0; c < 4; c++) { s += x[j][c]; ss += x[j][c] * x[j][c]; }
  }
  for (int o = 32; o > 0; o >>= 1) { s += __shfl_xor(s, o, 64); ss += __shfl_xor(ss, o, 64); }
  const float m = s * (1.f / 1024.f);
  const float rstd = rsqrtf(ss * (1.f / 1024.f) - m * m + 1e-5f);
#pragma unroll
  for (int j = 0; j < 4; j++) {
    f32x4 gg = *(const f32x4*)(g + j * 256 + lane * 4);
    f32x4 bb = *(const f32x4*)(b + j * 256 + lane * 4);
    f32x4 y;
#pragma unroll
    for (int c = 0; c < 4; c++) y[c] = (x[j][c] - m) * rstd * gg[c] + bb[c];
    *(f32x4*)(r + j * 256 + lane * 4) = y;
  }
}

extern "C" void kernel_launch(void* const* d_in, const int* in_sizes, int n_in,
                              void* d_out, int out_size, void* d_ws, size_t ws_size,
                              hipStream_t stream) {
  const float* text = (const float*)d_in[0];
  const float* audio = (const float*)d_in[1];
  const int* amask = (const int*)d_in[2];
  const float* ln_t_g = (const float*)d_in[3];
  const float* ln_t_b = (const float*)d_in[4];
  const float* ln_a_g = (const float*)d_in[5];
  const float* ln_a_b = (const float*)d_in[6];
  const float* Wq = (const float*)d_in[7];
  const float* bq = (const float*)d_in[8];
  const float* Wk = (const float*)d_in[9];
  const float* bk = (const float*)d_in[10];
  const float* Wv = (const float*)d_in[11];
  const float* bv = (const float*)d_in[12];
  const float* ln_p_g = (const float*)d_in[13];
  const float* ln_p_b = (const float*)d_in[14];

  char* p = (char*)d_ws;
  short* tb = (short*)p;  p += (size_t)32768 * 1024 * 2;   // 64 MB  (LN text, bf16)
  short* ab = (short*)p;  p += (size_t)65536 * 1024 * 2;   // 128 MB (LN audio, bf16)
  short* Wqt = (short*)p; p += (size_t)1024 * 1024 * 2;
  short* Wkt = (short*)p; p += (size_t)1024 * 1024 * 2;
  short* Wvt = (short*)p; p += (size_t)1024 * 1024 * 2;
  short* qb = (short*)p;  p += (size_t)32768 * 1024 * 2;   // 64 MB
  short* kb = (short*)p;  p += (size_t)65536 * 1024 * 2;   // 128 MB
  short* vTb = (short*)p; p += (size_t)32 * 1024 * 2048 * 2;  // 128 MB, [b][d][s]
  // P aliases tb+ab (dead once qb/kb/vTb are built; scores runs after)
  short* Pb = tb;
  (void)ws_size; (void)in_sizes; (void)n_in; (void)out_size;

  // 1. LN -> bf16
  ln_bf16_kernel<<<8192, 256, 0, stream>>>(text, ln_t_g, ln_t_b, tb);
  ln_bf16_kernel<<<16384, 256, 0, stream>>>(audio, ln_a_g, ln_a_b, ab);
  // 2. weight transpose+convert
  wtrans_kernel<<<dim3(32, 32), 256, 0, stream>>>(Wq, Wqt);
  wtrans_kernel<<<dim3(32, 32), 256, 0, stream>>>(Wk, Wkt);
  wtrans_kernel<<<dim3(32, 32), 256, 0, stream>>>(Wv, Wvt);
  // 3. q = tb @ Wqt^T + bq   [32768 x 1024]
  gemm8_kernel<0><<<dim3(4, 128, 1), 512, 0, stream>>>(
      tb, Wqt, qb, 1024, 1024, 0, 0, 0, bq, nullptr, 0.f);
  // 4. k = ab @ Wkt^T + bk   [65536 x 1024]
  gemm8_kernel<0><<<dim3(4, 256, 1), 512, 0, stream>>>(
      ab, Wkt, kb, 1024, 1024, 0, 0, 0, bk, nullptr, 0.f);
  // 5. vT[b][d][s] = (ab @ Wvt^T + bv)^T : A=Wvt (M=1024 d), B=ab[b] (N=2048 s)
  gemm8_kernel<3><<<dim3(8, 4, 32), 512, 0, stream>>>(
      Wvt, ab, vTb, 1024, 2048, 0, (long)2048 * 1024, (long)1024 * 2048,
      bv, nullptr, 0.f);
  // 6. scores = q @ k^T * scale, masked -> P bf16 [32][1024][2048]
  gemm8_kernel<1><<<dim3(8, 4, 32), 512, 0, stream>>>(
      qb, kb, Pb, 1024, 2048, (long)1024 * 1024, (long)2048 * 1024,
      (long)1024 * 2048, nullptr, amask, 0.03125f);
  // 7. softmax rows of P, in place
  softmax_kernel<<<8192, 256, 0, stream>>>(Pb);
  // 8. cross = P @ vT^T -> d_out fp32 [32][1024][1024]
  gemm8_kernel<2><<<dim3(4, 4, 32), 512, 0, stream>>>(
      Pb, vTb, d_out, 2048, 1024, (long)1024 * 2048, (long)1024 * 2048,
      (long)1024 * 1024, nullptr, nullptr, 0.f);
  // 9. final LayerNorm in place on d_out
  final_ln_kernel<<<8192, 256, 0, stream>>>((float*)d_out, ln_p_g, ln_p_b);
}